// Round 12
// baseline (1191.736 us; speedup 1.0000x reference)
//
#include <hip/hip_runtime.h>
#include <hip/hip_bf16.h>

// TensorConvLayer: edge MLP (bf16 MFMA) -> tensor product (in-register) ->
// atomic scatter-mean -> batch norm.  fp32 I/O, bf16 internal GEMMs.
//
// R11 -> R12: register-cap postmortem. Every __launch_bounds__ cap run
// failed (R3 (512,6): absmax 0.496; R4/R11 (512,4): tripwire divergence +
// run-varying absmax) while every natural build is green (R1/R2/R10) --
// forced spills read stale scratch (run-dependent garbage). NEVER cap this
// kernel. Occupancy instead comes from naturally lower VGPR: R10's 128
// VGPRs are mostly the 9x-unrolled phase-2 weight loads (18 bf16x8 in
// flight = 72 VGPRs). Single change vs green R10: #pragma unroll 1 on the
// phase-2 mi loop -> 2 loads in flight -> VGPR ~100 -> 2 blocks/CU without
// any allocator coercion. Lost intra-wave ILP is replaced by inter-block TLP.

typedef __bf16 bf16_t;
typedef bf16_t bf16x8 __attribute__((ext_vector_type(8)));
typedef bf16_t bf16x4 __attribute__((ext_vector_type(4)));
typedef float  f32x4  __attribute__((ext_vector_type(4)));

__device__ __forceinline__ bf16_t f2bf(float f) {
  unsigned u = __builtin_bit_cast(unsigned, f);
  u += 0x7fffu + ((u >> 16) & 1u);          // round-to-nearest-even
  unsigned short s = (unsigned short)(u >> 16);
  return __builtin_bit_cast(bf16_t, s);
}

#define MFMA16(a, b, c) __builtin_amdgcn_mfma_f32_16x16x32_bf16((a), (b), (c), 0, 0, 0)

// ---------------------------------------------------------------- prep ----
// zero counts+stats; build bf16 transposed weights: w1t[n][k]=W1[k][n] (64x64),
// w2t[n][k]=W2[k][n] (576x64)
__global__ __launch_bounds__(256) void tcl_prep(
    const float* __restrict__ w1, const float* __restrict__ w2,
    unsigned short* __restrict__ w1tg, unsigned short* __restrict__ w2tg,
    int* __restrict__ cnt, float* __restrict__ stats, int NN)
{
  int t = blockIdx.x * 256 + threadIdx.x;
  if (t < NN) cnt[t] = 0;
  if (t < 48) stats[t] = 0.f;
  if (t < 64 * 64) {
    int k = t >> 6, n = t & 63;
    w1tg[n * 64 + k] = __builtin_bit_cast(unsigned short, f2bf(w1[t]));
  }
  if (t < 576 * 64) {
    int k = t / 576, n = t % 576;
    w2tg[n * 64 + k] = __builtin_bit_cast(unsigned short, f2bf(w2[t]));
  }
}

// ---------------------------------------------------------------- edge ----
__global__ __launch_bounds__(512, 2) void tcl_edge(
    const float* __restrict__ atom, const float* __restrict__ efeat,
    const float* __restrict__ esh, const int* __restrict__ eidx,
    const float* __restrict__ b1, const float* __restrict__ b2,
    const unsigned short* __restrict__ w1tg, const unsigned short* __restrict__ w2tg,
    float* __restrict__ sums, int* __restrict__ cnt, int E)
{
  // 47KB LDS. Natural register allocation (no cap -- caps miscompile, see
  // header). Weights stay in L2.
  __shared__ __attribute__((aligned(16))) bf16_t eflds[64][72];
  __shared__ __attribute__((aligned(16))) bf16_t hlds[64][72];
  __shared__ __attribute__((aligned(16))) float  xg[64][68];
  __shared__ __attribute__((aligned(16))) float  tpl[64][44];

  const int tid  = threadIdx.x;
  const int lane = tid & 63;
  const int wv   = tid >> 6;      // wave 0..7
  const int l15  = lane & 15;
  const int kg   = lane >> 4;     // 0..3
  const bf16_t* w1b = (const bf16_t*)w1tg;
  const bf16_t* w2b = (const bf16_t*)w2tg;

  for (long e0 = (long)blockIdx.x * 64; e0 < E; e0 += (long)gridDim.x * 64) {
    // ---------- phase 0: stage edge tile ----------
    for (int i = tid; i < 64 * 44; i += 512) ((float*)tpl)[i] = 0.f;
    {
      // edge_features -> bf16 LDS [edge][64]
      int e = tid >> 3, g = tid & 7;
      long ge = e0 + e;
      float4 va = {0, 0, 0, 0}, vb = {0, 0, 0, 0};
      if (ge < E) {
        const float4* p = (const float4*)(efeat + ge * 64 + g * 8);
        va = p[0]; vb = p[1];
      }
      bf16x8 v;
      v[0] = f2bf(va.x); v[1] = f2bf(va.y); v[2] = f2bf(va.z); v[3] = f2bf(va.w);
      v[4] = f2bf(vb.x); v[5] = f2bf(vb.y); v[6] = f2bf(vb.z); v[7] = f2bf(vb.w);
      *(bf16x8*)&eflds[e][g * 8] = v;
    }
    {
      // gather x = atom[dst], build premultiplied TP coefficient table xg:
      //  [0:16)  x0 raw
      //  [16:40) A11[i][c] = x1[i][c] * sh0*inv_s2/sqrt(8)
      //  [40:48) A10[i]    = (sum_c x1[i][c]*sh1[c]) * inv_s2/sqrt(24)
      //  [48:64) A0[i]     = x0[i] * sh0*inv_s2/4
      //  [64:67) sh1c[c]   = sh1[c] * inv_s2/4
      int e = lane, p = wv;
      long ge = e0 + e;
      if (ge < E) {
        int dst = eidx[ge];
        const float* xr = atom + (long)dst * 40;
        const float inv_s2 = 0.70710678118654752f;
        float sh0 = esh[ge * 4];
        if (p == 0) {
          for (int i = 0; i < 8; ++i) xg[e][i] = xr[i];
        } else if (p == 1) {
          for (int i = 8; i < 16; ++i) xg[e][i] = xr[i];
        } else if (p == 2) {
          float k11 = sh0 * inv_s2 * 0.35355339059327378f;
          for (int t2 = 0; t2 < 8; ++t2) xg[e][16 + t2] = xr[16 + t2] * k11;
        } else if (p == 3) {
          float k11 = sh0 * inv_s2 * 0.35355339059327378f;
          for (int t2 = 8; t2 < 16; ++t2) xg[e][16 + t2] = xr[16 + t2] * k11;
        } else if (p == 4) {
          float k11 = sh0 * inv_s2 * 0.35355339059327378f;
          for (int t2 = 16; t2 < 24; ++t2) xg[e][16 + t2] = xr[16 + t2] * k11;
        } else if (p == 5) {
          float s1x = esh[ge * 4 + 1], s1y = esh[ge * 4 + 2], s1z = esh[ge * 4 + 3];
          float k10 = inv_s2 * 0.20412414523193150f;
          for (int i = 0; i < 8; ++i) {
            float y = xr[16 + 3 * i] * s1x + xr[17 + 3 * i] * s1y + xr[18 + 3 * i] * s1z;
            xg[e][40 + i] = y * k10;
          }
        } else if (p == 6) {
          float k0s = sh0 * inv_s2 * 0.25f;
          for (int i = 0; i < 16; ++i) xg[e][48 + i] = xr[i] * k0s;
        } else {
          float ks = inv_s2 * 0.25f;
          for (int c = 0; c < 3; ++c) xg[e][64 + c] = esh[ge * 4 + 1 + c] * ks;
        }
      }
    }
    __syncthreads();

    // ---------- phase 1: GEMM1  h[j][e] = relu(W1T[j][:] . ef[e][:] + b1) ----------
    {
      int nf = wv & 3;               // edge-group of 16
      int mfb = (wv >> 2) * 2;       // hidden-group pair
      int erow = 16 * nf + l15;
      bf16x8 bfr0 = *(const bf16x8*)&eflds[erow][kg * 8];
      bf16x8 bfr1 = *(const bf16x8*)&eflds[erow][32 + kg * 8];
#pragma unroll
      for (int mi = 0; mi < 2; ++mi) {
        int mf = mfb + mi;
        const bf16_t* ap = w1b + (16 * mf + l15) * 64;
        bf16x8 a0 = *(const bf16x8*)(ap + kg * 8);
        bf16x8 a1 = *(const bf16x8*)(ap + 32 + kg * 8);
        f32x4 acc = {0.f, 0.f, 0.f, 0.f};
        acc = MFMA16(a0, bfr0, acc);
        acc = MFMA16(a1, bfr1, acc);
        int j0 = 16 * mf + 4 * kg;   // C/D: row=(lane>>4)*4+reg  (m89)
        bf16x4 hv;
#pragma unroll
        for (int r = 0; r < 4; ++r) {
          float v = acc[r] + b1[j0 + r];
          v = v > 0.f ? v : 0.f;
          hv[r] = f2bf(v);
        }
        *(bf16x4*)&hlds[erow][j0] = hv;
      }
    }
    __syncthreads();

    // ---------- phase 2: GEMM2 (w = W2T . h) fused with tensor product ----------
    {
      int nf2 = wv & 1;              // edge 32-half
      int mq  = wv >> 1;             // w-index quarter (9 mfrags)
      int eA = 16 * (2 * nf2 + 0) + l15;
      int eB = 16 * (2 * nf2 + 1) + l15;
      bf16x8 Bf00 = *(const bf16x8*)&hlds[eA][kg * 8];
      bf16x8 Bf01 = *(const bf16x8*)&hlds[eA][32 + kg * 8];
      bf16x8 Bf10 = *(const bf16x8*)&hlds[eB][kg * 8];
      bf16x8 Bf11 = *(const bf16x8*)&hlds[eB][32 + kg * 8];
      float sA0 = xg[eA][64], sA1 = xg[eA][65], sA2 = xg[eA][66];
      float sB0 = xg[eB][64], sB1 = xg[eB][65], sB2 = xg[eB][66];
      float o0[2][4] = {};           // out0 slice j = 4*kg + r
      float o1[2][4][3] = {};        // out1 slice j = 4*(kg&1) + r
      int kh = kg >> 1;
      // unroll 1: keep only one weight-load pair in flight (R10's full
      // unroll held 18 bf16x8 loads = 72 VGPRs -> 1 block/CU).
#pragma unroll 1
      for (int mi = 0; mi < 9; ++mi) {
        int mf = mq * 9 + mi;        // w-row block: k_w = 16*mf + 4*kg + r
        const bf16_t* ap = w2b + (16 * mf + l15) * 64;
        bf16x8 a0 = *(const bf16x8*)(ap + kg * 8);
        bf16x8 a1 = *(const bf16x8*)(ap + 32 + kg * 8);
        f32x4 bv = *(const f32x4*)&b2[16 * mf + 4 * kg];
        f32x4 accA = {0.f, 0.f, 0.f, 0.f};
        f32x4 accB = {0.f, 0.f, 0.f, 0.f};
        accA = MFMA16(a0, Bf00, accA);
        accA = MFMA16(a1, Bf01, accA);
        accB = MFMA16(a0, Bf10, accB);
        accB = MFMA16(a1, Bf11, accB);
        if (mf < 16) {                       // w00: i=mf, j=4*kg+r
          float cA = xg[eA][48 + mf], cB = xg[eB][48 + mf];
#pragma unroll
          for (int r = 0; r < 4; ++r) {
            o0[0][r] += (accA[r] + bv[r]) * cA;
            o0[1][r] += (accB[r] + bv[r]) * cB;
          }
        } else if (mf < 20) {                // w11: i=2*(mf-16)+kh, j=4*(kg&1)+r
          int i = 2 * (mf - 16) + kh;
          float cA0 = xg[eA][16 + 3 * i], cA1 = xg[eA][17 + 3 * i], cA2 = xg[eA][18 + 3 * i];
          float cB0 = xg[eB][16 + 3 * i], cB1 = xg[eB][17 + 3 * i], cB2 = xg[eB][18 + 3 * i];
#pragma unroll
          for (int r = 0; r < 4; ++r) {
            float wA = accA[r] + bv[r], wB = accB[r] + bv[r];
            o1[0][r][0] += wA * cA0; o1[0][r][1] += wA * cA1; o1[0][r][2] += wA * cA2;
            o1[1][r][0] += wB * cB0; o1[1][r][1] += wB * cB1; o1[1][r][2] += wB * cB2;
          }
        } else if (mf < 28) {                // w01: i=2*(mf-20)+kh, j=4*(kg&1)+r
          int i = 2 * (mf - 20) + kh;
          float xA = xg[eA][i], xB = xg[eB][i];
#pragma unroll
          for (int r = 0; r < 4; ++r) {
            float tA = (accA[r] + bv[r]) * xA;
            float tB = (accB[r] + bv[r]) * xB;
            o1[0][r][0] += tA * sA0; o1[0][r][1] += tA * sA1; o1[0][r][2] += tA * sA2;
            o1[1][r][0] += tB * sB0; o1[1][r][1] += tB * sB1; o1[1][r][2] += tB * sB2;
          }
        } else {                             // w10: i=mf-28, j=4*kg+r
          float cA = xg[eA][40 + mf - 28], cB = xg[eB][40 + mf - 28];
#pragma unroll
          for (int r = 0; r < 4; ++r) {
            o0[0][r] += (accA[r] + bv[r]) * cA;
            o0[1][r] += (accB[r] + bv[r]) * cB;
          }
        }
      }
      // reduce the 4 mq-waves (and kg i-halves) in LDS
      int j1 = 4 * (kg & 1);
#pragma unroll
      for (int r = 0; r < 4; ++r) {
        unsafeAtomicAdd(&tpl[eA][4 * kg + r], o0[0][r]);
        unsafeAtomicAdd(&tpl[eB][4 * kg + r], o0[1][r]);
      }
#pragma unroll
      for (int r = 0; r < 4; ++r)
#pragma unroll
        for (int c = 0; c < 3; ++c) {
          unsafeAtomicAdd(&tpl[eA][16 + 3 * (j1 + r) + c], o1[0][r][c]);
          unsafeAtomicAdd(&tpl[eB][16 + 3 * (j1 + r) + c], o1[1][r][c]);
        }
    }
    __syncthreads();

    // ---------- phase 3: scatter into node sums ----------
    {
      int e = tid >> 3, slot = tid & 7;
      long ge = e0 + e;
      if (ge < E) {
        int src = eidx[E + ge];
        float* srow = sums + (long)src * 40;
        int ob = slot * 5;
#pragma unroll
        for (int u = 0; u < 5; ++u) unsafeAtomicAdd(&srow[ob + u], tpl[e][ob + u]);
        if (slot == 0) atomicAdd(&cnt[src], 1);
      }
    }
    __syncthreads();
  }
}

// ---------------------------------------------------------------- node ----
// out = sums/max(cnt,1) + atom (in place in d_out); accumulate BN stats
__global__ __launch_bounds__(256) void tcl_node(
    const float* __restrict__ atom, const int* __restrict__ cnt,
    float* __restrict__ out, float* __restrict__ stats, int NN)
{
  int lane = threadIdx.x & 63;
  int gw = blockIdx.x * 4 + (threadIdx.x >> 6);
  int stride = gridDim.x * 4;
  float ssum = 0.f, ssq = 0.f, vsq = 0.f;
  for (int r = gw; r < NN; r += stride) {
    float c = (float)cnt[r];
    c = c > 1.f ? c : 1.f;
    if (lane < 40) {
      long idx = (long)r * 40 + lane;
      float o = out[idx] / c + atom[idx];
      out[idx] = o;
      if (lane < 16) { ssum += o; ssq += o * o; }
      else           { vsq += o * o; }
    }
  }
  if (lane < 16) {
    unsafeAtomicAdd(&stats[lane], ssum);
    unsafeAtomicAdd(&stats[16 + lane], ssq);
  } else if (lane < 40) {
    unsafeAtomicAdd(&stats[32 + (lane - 16) / 3], vsq);
  }
}

// ---------------------------------------------------------------- norm ----
__global__ __launch_bounds__(256) void tcl_norm(
    float* __restrict__ out, const float* __restrict__ stats,
    const float* __restrict__ bnw, const float* __restrict__ bnb, int NN)
{
  long idx = (long)blockIdx.x * 256 + threadIdx.x;
  long tot = (long)NN * 40;
  if (idx >= tot) return;
  int c = (int)(idx % 40);
  float o = out[idx];
  float invN = 1.0f / (float)NN;
  if (c < 16) {
    float mean = stats[c] * invN;
    float var  = stats[16 + c] * invN - mean * mean;
    float rs   = rsqrtf(var + 1e-5f);
    o = (o - mean) * rs * bnw[c] + bnb[c];
  } else {
    int m = (c - 16) / 3;
    float vn = stats[32 + m] * invN * (1.0f / 3.0f);
    float rs = rsqrtf(vn + 1e-5f);
    o = o * rs * bnw[16 + m];
  }
  out[idx] = o;
}

// -------------------------------------------------------------- launch ----
extern "C" void kernel_launch(void* const* d_in, const int* in_sizes, int n_in,
                              void* d_out, int out_size, void* d_ws, size_t ws_size,
                              hipStream_t stream)
{
  const float* atom  = (const float*)d_in[0];
  const float* efeat = (const float*)d_in[1];
  const float* esh   = (const float*)d_in[2];
  const int*   eidx  = (const int*)d_in[3];
  const float* w1    = (const float*)d_in[4];
  const float* b1    = (const float*)d_in[5];
  const float* w2    = (const float*)d_in[6];
  const float* b2    = (const float*)d_in[7];
  const float* bnw   = (const float*)d_in[8];
  const float* bnb   = (const float*)d_in[9];
  int E  = in_sizes[3] / 2;
  int NN = in_sizes[0] / 40;
  float* out = (float*)d_out;

  // workspace layout
  size_t off = 0;
  int* cnt = (int*)d_ws;                     off += (size_t)NN * 4;
  off = (off + 255) & ~(size_t)255;
  float* stats = (float*)((char*)d_ws + off); off += 48 * 4;
  off = (off + 255) & ~(size_t)255;
  unsigned short* w1tg = (unsigned short*)((char*)d_ws + off); off += 64 * 64 * 2;
  off = (off + 255) & ~(size_t)255;
  unsigned short* w2tg = (unsigned short*)((char*)d_ws + off);

  hipMemsetAsync(d_out, 0, (size_t)NN * 40 * sizeof(float), stream);
  tcl_prep<<<(NN + 255) / 256, 256, 0, stream>>>(w1, w2, w1tg, w2tg, cnt, stats, NN);
  tcl_edge<<<512, 512, 0, stream>>>(atom, efeat, esh, eidx, b1, b2, w1tg, w2tg, out, cnt, E);
  tcl_node<<<256, 256, 0, stream>>>(atom, cnt, out, stats, NN);
  tcl_norm<<<(int)(((long)NN * 40 + 255) / 256), 256, 0, stream>>>(out, stats, bnw, bnb, NN);
}

// Round 16
// 1024.517 us; speedup vs baseline: 1.1632x; 1.1632x over previous
//
#include <hip/hip_runtime.h>
#include <hip/hip_bf16.h>

// TensorConvLayer: edge MLP (bf16 MFMA) -> tensor product (in-register) ->
// atomic scatter-mean -> batch norm.  fp32 I/O, bf16 internal GEMMs.
//
// R16 = R13 resubmit x3 (three consecutive UnresponsiveContainer infra
// failures on container nice-broad-lively-roster; connection dies before
// source push, so no kernel signal. Byte-identical resubmit keeps the
// bisect clean for when a live chip is reacquired).
//
// R12 -> R13 (structural): occupancy pinned at 22.6% and edge at 850-1030us
// across LDS{141,47}KB x VGPR{76..128} x {atomic,sorted} -- the 512-thread
// 4-barrier tile structure itself is the latency wall. Rewrite: each WAVE
// owns 16 edges end-to-end, no __syncthreads at all (wave-private LDS slice,
// intra-wave lgkmcnt ordering). Blocks = 4 independent waves; ~26.6KB LDS,
// natural regalloc (no caps -- caps miscompile, R3/R4/R11). Same fragment
// layouts / TP math as the green R12 kernel; o1 kh-fold via shfl_xor(32)
// (exonerated by R8's construction test).

typedef __bf16 bf16_t;
typedef bf16_t bf16x8 __attribute__((ext_vector_type(8)));
typedef bf16_t bf16x4 __attribute__((ext_vector_type(4)));
typedef float  f32x4  __attribute__((ext_vector_type(4)));

__device__ __forceinline__ bf16_t f2bf(float f) {
  unsigned u = __builtin_bit_cast(unsigned, f);
  u += 0x7fffu + ((u >> 16) & 1u);          // round-to-nearest-even
  unsigned short s = (unsigned short)(u >> 16);
  return __builtin_bit_cast(bf16_t, s);
}

#define MFMA16(a, b, c) __builtin_amdgcn_mfma_f32_16x16x32_bf16((a), (b), (c), 0, 0, 0)

// ---------------------------------------------------------------- prep ----
__global__ __launch_bounds__(256) void tcl_prep(
    const float* __restrict__ w1, const float* __restrict__ w2,
    unsigned short* __restrict__ w1tg, unsigned short* __restrict__ w2tg,
    int* __restrict__ cnt, float* __restrict__ stats, int NN)
{
  int t = blockIdx.x * 256 + threadIdx.x;
  if (t < NN) cnt[t] = 0;
  if (t < 48) stats[t] = 0.f;
  if (t < 64 * 64) {
    int k = t >> 6, n = t & 63;
    w1tg[n * 64 + k] = __builtin_bit_cast(unsigned short, f2bf(w1[t]));
  }
  if (t < 576 * 64) {
    int k = t / 576, n = t % 576;
    w2tg[n * 64 + k] = __builtin_bit_cast(unsigned short, f2bf(w2[t]));
  }
}

// ---------------------------------------------------------------- edge ----
// One wave = 16 edges. lane = kg*16 + l15: l15 = edge-in-group, kg = K-slice.
__global__ __launch_bounds__(256) void tcl_edge(
    const float* __restrict__ atom, const float* __restrict__ efeat,
    const float* __restrict__ esh, const int* __restrict__ eidx,
    const float* __restrict__ b1, const float* __restrict__ b2,
    const unsigned short* __restrict__ w1tg, const unsigned short* __restrict__ w2tg,
    float* __restrict__ sums, int* __restrict__ cnt, int E)
{
  // wave-private LDS slices -> no __syncthreads anywhere.
  __shared__ __attribute__((aligned(16))) bf16_t hlds[4][16][72];
  __shared__ __attribute__((aligned(16))) float  xg[4][16][68];

  const int tid  = threadIdx.x;
  const int wv   = tid >> 6;      // wave 0..3 (independent)
  const int lane = tid & 63;
  const int l15  = lane & 15;     // edge in group
  const int kg   = lane >> 4;     // K-slice 0..3
  const int kh   = kg >> 1;
  const bf16_t* w1b = (const bf16_t*)w1tg;
  const bf16_t* w2b = (const bf16_t*)w2tg;

  const int ngr = (E + 15) >> 4;
  const int gw0 = blockIdx.x * 4 + wv;
  const int gstride = gridDim.x * 4;

  for (int g = gw0; g < ngr; g += gstride) {
    long ge = (long)g * 16 + l15;
    bool v = ge < E;

    // ---- A: efeat -> B-fragments direct from global (full K=64 row) ----
    bf16x8 Bf0, Bf1;
    {
      float4 a = {0,0,0,0}, b = a, c = a, d = a;
      if (v) {
        const float4* p = (const float4*)(efeat + ge * 64 + kg * 8);
        a = p[0]; b = p[1];
        const float4* q = (const float4*)(efeat + ge * 64 + 32 + kg * 8);
        c = q[0]; d = q[1];
      }
      Bf0[0]=f2bf(a.x); Bf0[1]=f2bf(a.y); Bf0[2]=f2bf(a.z); Bf0[3]=f2bf(a.w);
      Bf0[4]=f2bf(b.x); Bf0[5]=f2bf(b.y); Bf0[6]=f2bf(b.z); Bf0[7]=f2bf(b.w);
      Bf1[0]=f2bf(c.x); Bf1[1]=f2bf(c.y); Bf1[2]=f2bf(c.z); Bf1[3]=f2bf(c.w);
      Bf1[4]=f2bf(d.x); Bf1[5]=f2bf(d.y); Bf1[6]=f2bf(d.z); Bf1[7]=f2bf(d.w);
    }

    // ---- B: premultiplied TP coefficient table (work split by kg) ----
    //  [0:16) x0 | [16:40) x1*sh0*c11 | [40:48) (x1.sh1)*c10
    //  [48:64) x0*sh0*c00 | [64:67) sh1*c01
    if (v) {
      int dst = eidx[ge];
      const float* xr = atom + (long)dst * 40;
      const float inv_s2 = 0.70710678118654752f;
      if (kg == 0) {
        for (int i = 0; i < 16; ++i) xg[wv][l15][i] = xr[i];
      } else if (kg == 1) {
        float k11 = esh[ge * 4] * inv_s2 * 0.35355339059327378f;
        for (int t2 = 0; t2 < 24; ++t2) xg[wv][l15][16 + t2] = xr[16 + t2] * k11;
      } else if (kg == 2) {
        float s1x = esh[ge * 4 + 1], s1y = esh[ge * 4 + 2], s1z = esh[ge * 4 + 3];
        float k10 = inv_s2 * 0.20412414523193150f;
        for (int i = 0; i < 8; ++i) {
          float y = xr[16 + 3 * i] * s1x + xr[17 + 3 * i] * s1y + xr[18 + 3 * i] * s1z;
          xg[wv][l15][40 + i] = y * k10;
        }
        float ks = inv_s2 * 0.25f;
        xg[wv][l15][64] = s1x * ks;
        xg[wv][l15][65] = s1y * ks;
        xg[wv][l15][66] = s1z * ks;
      } else {
        float k0s = esh[ge * 4] * inv_s2 * 0.25f;
        for (int i = 0; i < 16; ++i) xg[wv][l15][48 + i] = xr[i] * k0s;
      }
    }

    // ---- C: GEMM1  h[j][e] = relu(W1T . ef + b1), all 64 rows ----
    for (int mf = 0; mf < 4; ++mf) {
      const bf16_t* ap = w1b + (16 * mf + l15) * 64;
      bf16x8 a0 = *(const bf16x8*)(ap + kg * 8);
      bf16x8 a1 = *(const bf16x8*)(ap + 32 + kg * 8);
      f32x4 acc = {0.f, 0.f, 0.f, 0.f};
      acc = MFMA16(a0, Bf0, acc);
      acc = MFMA16(a1, Bf1, acc);
      int j0 = 16 * mf + 4 * kg;   // C/D: col=lane&15 (edge), row=(lane>>4)*4+r
      bf16x4 hv;
#pragma unroll
      for (int r = 0; r < 4; ++r) {
        float x = acc[r] + b1[j0 + r];
        x = x > 0.f ? x : 0.f;
        hv[r] = f2bf(x);
      }
      *(bf16x4*)&hlds[wv][l15][j0] = hv;
    }

    // ---- D: re-read h as B-fragments (same wave; lgkmcnt ordering) ----
    bf16x8 Bh0 = *(const bf16x8*)&hlds[wv][l15][kg * 8];
    bf16x8 Bh1 = *(const bf16x8*)&hlds[wv][l15][32 + kg * 8];
    float s0 = xg[wv][l15][64], s1 = xg[wv][l15][65], s2 = xg[wv][l15][66];

    // ---- E: GEMM2 (all 36 w-row blocks) fused with tensor product ----
    float o0[4] = {};        // out0 slice j = 4*kg + r (complete per lane)
    float o1[4][3] = {};     // out1 slice j = 4*(kg&1) + r (partial: this kh)
    for (int mf = 0; mf < 36; ++mf) {
      const bf16_t* ap = w2b + (16 * mf + l15) * 64;
      bf16x8 a0 = *(const bf16x8*)(ap + kg * 8);
      bf16x8 a1 = *(const bf16x8*)(ap + 32 + kg * 8);
      f32x4 bv = *(const f32x4*)&b2[16 * mf + 4 * kg];
      f32x4 acc = {0.f, 0.f, 0.f, 0.f};
      acc = MFMA16(a0, Bh0, acc);
      acc = MFMA16(a1, Bh1, acc);
      if (mf < 16) {                       // w00: i=mf, j=4*kg+r
        float cA = xg[wv][l15][48 + mf];
#pragma unroll
        for (int r = 0; r < 4; ++r) o0[r] += (acc[r] + bv[r]) * cA;
      } else if (mf < 20) {                // w11: i=2*(mf-16)+kh, j=4*(kg&1)+r
        int i = 2 * (mf - 16) + kh;
        float c0 = xg[wv][l15][16 + 3 * i], c1 = xg[wv][l15][17 + 3 * i], c2 = xg[wv][l15][18 + 3 * i];
#pragma unroll
        for (int r = 0; r < 4; ++r) {
          float wA = acc[r] + bv[r];
          o1[r][0] += wA * c0; o1[r][1] += wA * c1; o1[r][2] += wA * c2;
        }
      } else if (mf < 28) {                // w01: i=2*(mf-20)+kh, j=4*(kg&1)+r
        int i = 2 * (mf - 20) + kh;
        float xA = xg[wv][l15][i];
#pragma unroll
        for (int r = 0; r < 4; ++r) {
          float tA = (acc[r] + bv[r]) * xA;
          o1[r][0] += tA * s0; o1[r][1] += tA * s1; o1[r][2] += tA * s2;
        }
      } else {                             // w10: i=mf-28, j=4*kg+r
        float cA = xg[wv][l15][40 + mf - 28];
#pragma unroll
        for (int r = 0; r < 4; ++r) o0[r] += (acc[r] + bv[r]) * cA;
      }
    }
    // fold kh pairs (lane^32: kg<->kg^2, same l15); lanes kg<2 hold full o1
    float o1f[4][3];
#pragma unroll
    for (int r = 0; r < 4; ++r)
#pragma unroll
      for (int c = 0; c < 3; ++c)
        o1f[r][c] = o1[r][c] + __shfl_xor(o1[r][c], 32);

    // ---- F: direct atomic scatter (16 + 24 + count per edge) ----
    if (v) {
      int src = eidx[E + ge];
      float* srow = sums + (long)src * 40;
#pragma unroll
      for (int r = 0; r < 4; ++r) unsafeAtomicAdd(&srow[4 * kg + r], o0[r]);
      if (kg < 2) {
        int j1 = 4 * kg;
#pragma unroll
        for (int r = 0; r < 4; ++r)
#pragma unroll
          for (int c = 0; c < 3; ++c)
            unsafeAtomicAdd(&srow[16 + 3 * (j1 + r) + c], o1f[r][c]);
      }
      if (kg == 0) atomicAdd(&cnt[src], 1);
    }
  }
}

// ---------------------------------------------------------------- node ----
__global__ __launch_bounds__(256) void tcl_node(
    const float* __restrict__ atom, const int* __restrict__ cnt,
    float* __restrict__ out, float* __restrict__ stats, int NN)
{
  int lane = threadIdx.x & 63;
  int gw = blockIdx.x * 4 + (threadIdx.x >> 6);
  int stride = gridDim.x * 4;
  float ssum = 0.f, ssq = 0.f, vsq = 0.f;
  for (int r = gw; r < NN; r += stride) {
    float c = (float)cnt[r];
    c = c > 1.f ? c : 1.f;
    if (lane < 40) {
      long idx = (long)r * 40 + lane;
      float o = out[idx] / c + atom[idx];
      out[idx] = o;
      if (lane < 16) { ssum += o; ssq += o * o; }
      else           { vsq += o * o; }
    }
  }
  if (lane < 16) {
    unsafeAtomicAdd(&stats[lane], ssum);
    unsafeAtomicAdd(&stats[16 + lane], ssq);
  } else if (lane < 40) {
    unsafeAtomicAdd(&stats[32 + (lane - 16) / 3], vsq);
  }
}

// ---------------------------------------------------------------- norm ----
__global__ __launch_bounds__(256) void tcl_norm(
    float* __restrict__ out, const float* __restrict__ stats,
    const float* __restrict__ bnw, const float* __restrict__ bnb, int NN)
{
  long idx = (long)blockIdx.x * 256 + threadIdx.x;
  long tot = (long)NN * 40;
  if (idx >= tot) return;
  int c = (int)(idx % 40);
  float o = out[idx];
  float invN = 1.0f / (float)NN;
  if (c < 16) {
    float mean = stats[c] * invN;
    float var  = stats[16 + c] * invN - mean * mean;
    float rs   = rsqrtf(var + 1e-5f);
    o = (o - mean) * rs * bnw[c] + bnb[c];
  } else {
    int m = (c - 16) / 3;
    float vn = stats[32 + m] * invN * (1.0f / 3.0f);
    float rs = rsqrtf(vn + 1e-5f);
    o = o * rs * bnw[16 + m];
  }
  out[idx] = o;
}

// -------------------------------------------------------------- launch ----
extern "C" void kernel_launch(void* const* d_in, const int* in_sizes, int n_in,
                              void* d_out, int out_size, void* d_ws, size_t ws_size,
                              hipStream_t stream)
{
  const float* atom  = (const float*)d_in[0];
  const float* efeat = (const float*)d_in[1];
  const float* esh   = (const float*)d_in[2];
  const int*   eidx  = (const int*)d_in[3];
  const float* w1    = (const float*)d_in[4];
  const float* b1    = (const float*)d_in[5];
  const float* w2    = (const float*)d_in[6];
  const float* b2    = (const float*)d_in[7];
  const float* bnw   = (const float*)d_in[8];
  const float* bnb   = (const float*)d_in[9];
  int E  = in_sizes[3] / 2;
  int NN = in_sizes[0] / 40;
  float* out = (float*)d_out;

  // workspace layout
  size_t off = 0;
  int* cnt = (int*)d_ws;                     off += (size_t)NN * 4;
  off = (off + 255) & ~(size_t)255;
  float* stats = (float*)((char*)d_ws + off); off += 48 * 4;
  off = (off + 255) & ~(size_t)255;
  unsigned short* w1tg = (unsigned short*)((char*)d_ws + off); off += 64 * 64 * 2;
  off = (off + 255) & ~(size_t)255;
  unsigned short* w2tg = (unsigned short*)((char*)d_ws + off);

  hipMemsetAsync(d_out, 0, (size_t)NN * 40 * sizeof(float), stream);
  tcl_prep<<<(NN + 255) / 256, 256, 0, stream>>>(w1, w2, w1tg, w2tg, cnt, stats, NN);
  tcl_edge<<<2048, 256, 0, stream>>>(atom, efeat, esh, eidx, b1, b2, w1tg, w2tg, out, cnt, E);
  tcl_node<<<256, 256, 0, stream>>>(atom, cnt, out, stats, NN);
  tcl_norm<<<(int)(((long)NN * 40 + 255) / 256), 256, 0, stream>>>(out, stats, bnw, bnb, NN);
}